// Round 21
// baseline (379.133 us; speedup 1.0000x reference)
//
#include <hip/hip_runtime.h>
#include <hip/hip_bf16.h>

// GCN 3-layer forward, MI355X. Round 21 (base = r20):
//  - bnstats FUSED into the gather (k_gatherBN): grid-stride 2048 blocks,
//    eg==0 lanes accumulate (sum,sumsq) of their 8 channels across ~49 nodes
//    in registers, LDS block-reduce, 256 global atomics/block (524K total,
//    amortized -- not the per-edge atomic pathology). Deletes 2 dispatches
//    + 2x 25.6MB bufB re-read. Stats now on fp32 pre-rounding values
//    (delta ~1e-3 relative on var).
//  - Rest = r20: direct-scatter partA (8KB LDS), counting-sort partB,
//    packed 4B edges, y=dinv*xw convention, BK=48, bf16 hidden states,
//    LDS-free MFMA GEMMs, BN-finalize inlined in gemm2/dotW3. 9 dispatches.

#define HID 128
#define BN_EPS 1e-5f
#define BK 48          // bucket capacity (P(Poisson(16)>48) ~ 1e-10)
#define NPB 128        // nodes per bin
#define NBMAX 1024     // max bins supported (N <= 131072)
#define CH_A 4096      // edges per partA block
#define BINCAP 2432    // bin edge capacity (mean 2048, +8.5 sigma)
#define GB_GATHER 2048 // gather grid blocks (8/CU)

typedef __attribute__((ext_vector_type(8))) short bf16x8;
typedef __attribute__((ext_vector_type(4))) float f32x4;

static inline size_t alignup(size_t x){ return (x + 255) & ~(size_t)255; }

// ---------------- helpers ----------------

static __device__ inline float2 bf16pair(unsigned int u){
  __hip_bfloat162 h = *(__hip_bfloat162*)&u;
  return __bfloat1622float2(h);
}

static __device__ inline unsigned int packpair(float x, float y){
  __hip_bfloat162 p = __float22bfloat162_rn({x, y});
  return *(unsigned int*)&p;
}

static __device__ inline uint2 pack_bf16x4(float4 a){
  uint2 r;
  r.x = packpair(a.x, a.y);
  r.y = packpair(a.z, a.w);
  return r;
}

static __device__ inline unsigned short bfbits(float v){
  __hip_bfloat16 h = __float2bfloat16(v);
  return *(unsigned short*)&h;
}

// decode packed edge: src = e & 0x1FFFF; w = float(bf16 bits = e>>17, sign 0)
static __device__ inline float edge_w(unsigned int e){
  unsigned int fb = (e >> 17) << 16;
  return __uint_as_float(fb);
}

// weight transposes + all zero-init in one launch: 128 blocks x 256 threads.
__global__ void k_wtprep2(const float* __restrict__ W1, const float* __restrict__ W2,
                          unsigned short* __restrict__ wt1, unsigned short* __restrict__ wt2,
                          float* __restrict__ stats1, float* __restrict__ stats2,
                          int* __restrict__ binCur){
  int idx = blockIdx.x*256 + threadIdx.x;   // 0..32767
  if (idx < 256) stats1[idx] = 0.f;
  else if (idx < 512) stats2[idx - 256] = 0.f;
  else if (idx < 512 + NBMAX) binCur[idx - 512] = 0;
  const float* Wg = (idx < 16384) ? W1 : W2;
  unsigned short* WTg = (idx < 16384) ? wt1 : wt2;
  int i = idx & 16383;
  int k   = i >> 7;
  int col = i & 127;
  WTg[(size_t)col*128 + k] = bfbits(Wg[(size_t)k*128 + col]);
}

// ---------------- CSR build partA: histogram + direct scatter ----------------

__global__ __launch_bounds__(256) void k_partA(const int* __restrict__ ei,
    const float* __restrict__ attr, int* __restrict__ binCur,
    int2* __restrict__ binbuf, int E){
  __shared__ int hist[NBMAX];    // pass1: histogram; pass2: local cursor
  __shared__ int gbase[NBMAX];
  int e0 = blockIdx.x * CH_A;
  for (int b = threadIdx.x; b < NBMAX; b += 256) hist[b] = 0;
  __syncthreads();
  #pragma unroll
  for (int k = 0; k < CH_A/256; ++k){
    int e = e0 + k*256 + threadIdx.x;
    if (e < E) atomicAdd(&hist[ei[E + e] >> 7], 1);
  }
  __syncthreads();
  for (int b = threadIdx.x; b < NBMAX; b += 256){
    int h = hist[b];
    gbase[b] = h ? atomicAdd(&binCur[b], h) : 0;
    hist[b] = 0;
  }
  __syncthreads();
  #pragma unroll
  for (int k = 0; k < CH_A/256; ++k){
    int e = e0 + k*256 + threadIdx.x;
    if (e < E){
      int d = ei[E + e];
      int s = ei[e];
      int bin = d >> 7;
      int p = atomicAdd(&hist[bin], 1);
      int off = gbase[bin] + p;
      if (off < BINCAP)
        binbuf[(size_t)bin*BINCAP + off] =
            make_int2(s | ((d & 127) << 17), __float_as_int(attr[e]));
    }
  }
}

// per bin: LDS node-buckets (packed 4B) + degsum -> dinv, dense writeout.
__global__ __launch_bounds__(256) void k_partB(const int2* __restrict__ binbuf,
    const int* __restrict__ binCur, unsigned int* __restrict__ csr,
    int* __restrict__ cnt, float* __restrict__ dinv, int N){
  __shared__ unsigned int lb[NPB*BK];   // 24 KB
  __shared__ int lcnt[NPB];
  int bin = blockIdx.x;
  int node0 = bin * NPB;
  for (int i = threadIdx.x; i < NPB; i += 256) lcnt[i] = 0;
  __syncthreads();
  int m = min(binCur[bin], BINCAP);
  for (int i = threadIdx.x; i < m; i += 256){
    int2 rec = binbuf[(size_t)bin*BINCAP + i];
    int dlo = (rec.x >> 17) & 127;
    int s   = rec.x & 0x1FFFF;
    unsigned int wb = bfbits(__int_as_float(rec.y)) & 0x7FFF;
    int p = atomicAdd(&lcnt[dlo], 1);
    if (p < BK) lb[dlo*BK + p] = (unsigned int)s | (wb << 17);
  }
  __syncthreads();
  if (threadIdx.x < NPB){
    int node = node0 + threadIdx.x;
    if (node < N){
      int c = min(lcnt[threadIdx.x], BK);
      float s = 0.f;
      for (int k = 0; k < c; ++k) s += edge_w(lb[threadIdx.x*BK + k]);
      cnt[node] = c;
      dinv[node] = 1.0f / sqrtf(1.0f + s);
    }
  }
  int lim = min(NPB, N - node0) * BK;
  for (int i = threadIdx.x; i < lim; i += 256)
    csr[(size_t)node0*BK + i] = lb[i];
}

// ---------------- MFMA GEMM (no LDS staging; optional inline BN coef) ------
// C[n,128](bf16 pairs, node-major) = dinv[row] * ( act(A[n,128]) @ W ).
template<bool BN, bool AB16>
__device__ inline void gemm_body(const void* __restrict__ Av,
    const unsigned short* __restrict__ WTg,
    const float* __restrict__ stats, const float* __restrict__ gamma,
    const float* __restrict__ beta, const float* __restrict__ dinv,
    unsigned int* __restrict__ C, int n, int bid){
  __shared__ float coefL[256];
  if (BN){
    if (threadIdx.x < 128){
      int c = threadIdx.x;
      float inv_n = 1.0f / (float)n;
      float mean = stats[c] * inv_n;
      float var = fmaxf(stats[128 + c] * inv_n - mean*mean, 0.f);
      float sc = gamma[c] / sqrtf(var + BN_EPS);
      coefL[c] = sc;
      coefL[128 + c] = fmaf(-mean, sc, beta[c]);
    }
    __syncthreads();
  }
  int lane = threadIdx.x & 63;
  int wv4  = threadIdx.x >> 6;      // wave 0..3
  int l16  = lane & 15;
  int kg   = lane >> 4;             // 0..3
  int row_base = bid*128 + wv4*32;
  int nm1 = n - 1;
  int a0row = min(row_base + l16,      nm1);
  int a1row = min(row_base + 16 + l16, nm1);

  f32x4 acc[2][8] = {};
  #pragma unroll
  for (int k0 = 0; k0 < 128; k0 += 32){
    int k = k0 + kg*8;
    float4 sca, scb, sha, shb;
    if (BN){
      sca = *(const float4*)(coefL + k);
      scb = *(const float4*)(coefL + k + 4);
      sha = *(const float4*)(coefL + 128 + k);
      shb = *(const float4*)(coefL + 128 + k + 4);
    }
    bf16x8 a0, a1;
    if constexpr (AB16){
      const unsigned int* A = (const unsigned int*)Av;
      uint4 u0 = *(const uint4*)(A + (size_t)a0row*64 + (k >> 1));
      uint4 u1 = *(const uint4*)(A + (size_t)a1row*64 + (k >> 1));
      #pragma unroll
      for (int half = 0; half < 2; ++half){
        uint4 u = half ? u1 : u0;
        float2 p0 = bf16pair(u.x), p1 = bf16pair(u.y);
        float2 p2 = bf16pair(u.z), p3 = bf16pair(u.w);
        if (BN){
          p0.x = fmaxf(fmaf(p0.x, sca.x, sha.x), 0.f);
          p0.y = fmaxf(fmaf(p0.y, sca.y, sha.y), 0.f);
          p1.x = fmaxf(fmaf(p1.x, sca.z, sha.z), 0.f);
          p1.y = fmaxf(fmaf(p1.y, sca.w, sha.w), 0.f);
          p2.x = fmaxf(fmaf(p2.x, scb.x, shb.x), 0.f);
          p2.y = fmaxf(fmaf(p2.y, scb.y, shb.y), 0.f);
          p3.x = fmaxf(fmaf(p3.x, scb.z, shb.z), 0.f);
          p3.y = fmaxf(fmaf(p3.y, scb.w, shb.w), 0.f);
        }
        union { bf16x8 v; unsigned int u[4]; } c;
        c.u[0] = packpair(p0.x, p0.y);
        c.u[1] = packpair(p1.x, p1.y);
        c.u[2] = packpair(p2.x, p2.y);
        c.u[3] = packpair(p3.x, p3.y);
        if (half) a1 = c.v; else a0 = c.v;
      }
    } else {
      const float* A = (const float*)Av;
      float4 lo0 = *(const float4*)(A + (size_t)a0row*HID + k);
      float4 hi0 = *(const float4*)(A + (size_t)a0row*HID + k + 4);
      float4 lo1 = *(const float4*)(A + (size_t)a1row*HID + k);
      float4 hi1 = *(const float4*)(A + (size_t)a1row*HID + k + 4);
      union { bf16x8 v; uint2 u[2]; } a0c, a1c;
      a0c.u[0] = pack_bf16x4(lo0); a0c.u[1] = pack_bf16x4(hi0);
      a1c.u[0] = pack_bf16x4(lo1); a1c.u[1] = pack_bf16x4(hi1);
      a0 = a0c.v; a1 = a1c.v;
    }
    #pragma unroll
    for (int ct = 0; ct < 8; ++ct){
      int col = ct*16 + l16;
      bf16x8 b = *(const bf16x8*)(WTg + (size_t)col*128 + k);
      acc[0][ct] = __builtin_amdgcn_mfma_f32_16x16x32_bf16(a0, b, acc[0][ct], 0,0,0);
      acc[1][ct] = __builtin_amdgcn_mfma_f32_16x16x32_bf16(a1, b, acc[1][ct], 0,0,0);
    }
  }

  #pragma unroll
  for (int rt = 0; rt < 2; ++rt){
    int growb = row_base + rt*16 + kg*4;
    #pragma unroll
    for (int r = 0; r < 4; ++r){
      int grow = growb + r;
      bool ok = (grow < n) && !(lane & 1);
      float dv = ok ? dinv[grow] : 0.f;
      #pragma unroll
      for (int ct = 0; ct < 8; ++ct){
        float v = acc[rt][ct][r];
        float o = __shfl_xor(v, 1);
        if (ok)
          C[(size_t)grow*64 + ct*8 + (l16 >> 1)] = packpair(v*dv, o*dv);
      }
    }
  }
}

__global__ __launch_bounds__(256) void k_gemm_mfma_s(const float* __restrict__ A,
    const unsigned short* __restrict__ WTg, const float* __restrict__ dinv,
    unsigned int* __restrict__ C, int n){
  gemm_body<false,false>(A, WTg, nullptr, nullptr, nullptr, dinv, C, n, blockIdx.x);
}

__global__ __launch_bounds__(256) void k_gemm_mfma_bn16_s(const unsigned int* __restrict__ A,
    const unsigned short* __restrict__ WTg, const float* __restrict__ stats,
    const float* __restrict__ gamma, const float* __restrict__ beta,
    const float* __restrict__ dinv, unsigned int* __restrict__ C, int n){
  gemm_body<true,true>(A, WTg, stats, gamma, beta, dinv, C, n, blockIdx.x);
}

// ---------------- gather + fused BN stats ----------------

struct Acc8 { float a0,a1,a2,a3,a4,a5,a6,a7; };

static __device__ inline void fma8(Acc8& a, uint4 v, float wt){
  float2 p0 = bf16pair(v.x), p1 = bf16pair(v.y);
  float2 p2 = bf16pair(v.z), p3 = bf16pair(v.w);
  a.a0 = fmaf(wt, p0.x, a.a0); a.a1 = fmaf(wt, p0.y, a.a1);
  a.a2 = fmaf(wt, p1.x, a.a2); a.a3 = fmaf(wt, p1.y, a.a3);
  a.a4 = fmaf(wt, p2.x, a.a4); a.a5 = fmaf(wt, p2.y, a.a5);
  a.a6 = fmaf(wt, p3.x, a.a6); a.a7 = fmaf(wt, p3.y, a.a7);
}

// out[node] = pack( b + dinv[node]*( y[node] + sum_j attr_j*y[src_j] ) )
// Grid-stride (GB_GATHER blocks); eg==0 lanes accumulate per-channel
// (sum, sumsq) in registers; LDS block-reduce; 256 global atomics/block.
__global__ __launch_bounds__(256) void k_gatherBN(const unsigned int* __restrict__ yb,
    const unsigned int* __restrict__ csr, const int* __restrict__ cnt,
    const float* __restrict__ dinv, const float* __restrict__ bias,
    unsigned int* __restrict__ out, float* __restrict__ stats, int n){
  __shared__ float lsum[128], lsq[128];
  if (threadIdx.x < 128) lsum[threadIdx.x] = 0.f;
  else lsq[threadIdx.x - 128] = 0.f;
  __syncthreads();
  int lane = threadIdx.x & 63;
  int wv  = threadIdx.x >> 6;
  int l16 = lane & 15;
  int eg  = lane >> 4;
  float4 b0 = *(const float4*)(bias + l16*8);
  float4 b1 = *(const float4*)(bias + l16*8 + 4);
  float ts0=0,ts1=0,ts2=0,ts3=0,ts4=0,ts5=0,ts6=0,ts7=0;
  float tq0=0,tq1=0,tq2=0,tq3=0,tq4=0,tq5=0,tq6=0,tq7=0;

  for (int node = blockIdx.x*4 + wv; node < n; node += GB_GATHER*4){
    size_t base = (size_t)node*BK;
    int m = min(cnt[node], BK);
    Acc8 a = {0,0,0,0,0,0,0,0};
    float di = 0.f;
    if (eg == 0){
      di = dinv[node];
      uint4 sv = *(const uint4*)(yb + (size_t)node*64 + l16*4);
      float2 p0 = bf16pair(sv.x), p1 = bf16pair(sv.y);
      float2 p2 = bf16pair(sv.z), p3 = bf16pair(sv.w);
      a.a0 = p0.x; a.a1 = p0.y; a.a2 = p1.x; a.a3 = p1.y;
      a.a4 = p2.x; a.a5 = p2.y; a.a6 = p3.x; a.a7 = p3.y;
    }
    int j = eg;
    for (; j + 12 < m; j += 16){
      unsigned int e0 = csr[base + j];
      unsigned int e1 = csr[base + j + 4];
      unsigned int e2 = csr[base + j + 8];
      unsigned int e3 = csr[base + j + 12];
      uint4 v0 = *(const uint4*)(yb + (size_t)(e0 & 0x1FFFF)*64 + l16*4);
      uint4 v1 = *(const uint4*)(yb + (size_t)(e1 & 0x1FFFF)*64 + l16*4);
      uint4 v2 = *(const uint4*)(yb + (size_t)(e2 & 0x1FFFF)*64 + l16*4);
      uint4 v3 = *(const uint4*)(yb + (size_t)(e3 & 0x1FFFF)*64 + l16*4);
      fma8(a, v0, edge_w(e0));
      fma8(a, v1, edge_w(e1));
      fma8(a, v2, edge_w(e2));
      fma8(a, v3, edge_w(e3));
    }
    for (; j < m; j += 4){
      unsigned int ea = csr[base + j];
      uint4 va = *(const uint4*)(yb + (size_t)(ea & 0x1FFFF)*64 + l16*4);
      fma8(a, va, edge_w(ea));
    }
    a.a0 += __shfl_xor(a.a0, 16); a.a1 += __shfl_xor(a.a1, 16);
    a.a2 += __shfl_xor(a.a2, 16); a.a3 += __shfl_xor(a.a3, 16);
    a.a4 += __shfl_xor(a.a4, 16); a.a5 += __shfl_xor(a.a5, 16);
    a.a6 += __shfl_xor(a.a6, 16); a.a7 += __shfl_xor(a.a7, 16);
    a.a0 += __shfl_xor(a.a0, 32); a.a1 += __shfl_xor(a.a1, 32);
    a.a2 += __shfl_xor(a.a2, 32); a.a3 += __shfl_xor(a.a3, 32);
    a.a4 += __shfl_xor(a.a4, 32); a.a5 += __shfl_xor(a.a5, 32);
    a.a6 += __shfl_xor(a.a6, 32); a.a7 += __shfl_xor(a.a7, 32);
    if (eg == 0){
      float f0 = fmaf(di, a.a0, b0.x), f1 = fmaf(di, a.a1, b0.y);
      float f2 = fmaf(di, a.a2, b0.z), f3 = fmaf(di, a.a3, b0.w);
      float f4 = fmaf(di, a.a4, b1.x), f5 = fmaf(di, a.a5, b1.y);
      float f6 = fmaf(di, a.a6, b1.z), f7 = fmaf(di, a.a7, b1.w);
      uint4 r;
      r.x = packpair(f0, f1);
      r.y = packpair(f2, f3);
      r.z = packpair(f4, f5);
      r.w = packpair(f6, f7);
      *(uint4*)(out + (size_t)node*64 + l16*4) = r;
      ts0 += f0; ts1 += f1; ts2 += f2; ts3 += f3;
      ts4 += f4; ts5 += f5; ts6 += f6; ts7 += f7;
      tq0 = fmaf(f0,f0,tq0); tq1 = fmaf(f1,f1,tq1);
      tq2 = fmaf(f2,f2,tq2); tq3 = fmaf(f3,f3,tq3);
      tq4 = fmaf(f4,f4,tq4); tq5 = fmaf(f5,f5,tq5);
      tq6 = fmaf(f6,f6,tq6); tq7 = fmaf(f7,f7,tq7);
    }
  }

  if (eg == 0){
    int c = l16*8;
    atomicAdd(&lsum[c+0], ts0); atomicAdd(&lsum[c+1], ts1);
    atomicAdd(&lsum[c+2], ts2); atomicAdd(&lsum[c+3], ts3);
    atomicAdd(&lsum[c+4], ts4); atomicAdd(&lsum[c+5], ts5);
    atomicAdd(&lsum[c+6], ts6); atomicAdd(&lsum[c+7], ts7);
    atomicAdd(&lsq[c+0], tq0); atomicAdd(&lsq[c+1], tq1);
    atomicAdd(&lsq[c+2], tq2); atomicAdd(&lsq[c+3], tq3);
    atomicAdd(&lsq[c+4], tq4); atomicAdd(&lsq[c+5], tq5);
    atomicAdd(&lsq[c+6], tq6); atomicAdd(&lsq[c+7], tq7);
  }
  __syncthreads();
  if (threadIdx.x < 128) atomicAdd(&stats[threadIdx.x], lsum[threadIdx.x]);
  else atomicAdd(&stats[threadIdx.x], lsq[threadIdx.x - 128]);
}

// y3[row] = dinv[row] * sum_c relu(bn2(h[row][c])) * W3[c]; BN coef inline.
__global__ __launch_bounds__(256) void k_dotW3(const unsigned int* __restrict__ h,
    const float* __restrict__ stats, const float* __restrict__ gamma,
    const float* __restrict__ beta, const float* __restrict__ W3,
    const float* __restrict__ dinv, float* __restrict__ y3, int n){
  __shared__ float coefL[256];
  if (threadIdx.x < 128){
    int c = threadIdx.x;
    float inv_n = 1.0f / (float)n;
    float mean = stats[c] * inv_n;
    float var = fmaxf(stats[128 + c] * inv_n - mean*mean, 0.f);
    float sc = gamma[c] / sqrtf(var + BN_EPS);
    coefL[c] = sc;
    coefL[128 + c] = fmaf(-mean, sc, beta[c]);
  }
  __syncthreads();
  int lane = threadIdx.x & 31;
  int row = blockIdx.x*8 + (threadIdx.x >> 5);
  if (row >= n) return;
  uint2 u = *(const uint2*)(h + (size_t)row*64 + lane*2);
  float2 va = bf16pair(u.x), vb = bf16pair(u.y);
  float4 sc = *(const float4*)(coefL + lane*4);
  float4 sh = *(const float4*)(coefL + 128 + lane*4);
  float4 w  = *(const float4*)(W3 + lane*4);
  float acc = fmaxf(fmaf(va.x, sc.x, sh.x), 0.f) * w.x
            + fmaxf(fmaf(va.y, sc.y, sh.y), 0.f) * w.y
            + fmaxf(fmaf(vb.x, sc.z, sh.z), 0.f) * w.z
            + fmaxf(fmaf(vb.y, sc.w, sh.w), 0.f) * w.w;
  #pragma unroll
  for (int mm = 1; mm < 32; mm <<= 1) acc += __shfl_xor(acc, mm, 32);
  if (lane == 0) y3[row] = acc * dinv[row];
}

__global__ void k_gather1(const float* __restrict__ y3, const unsigned int* __restrict__ csr,
    const int* __restrict__ cnt, const float* __restrict__ dinv,
    const float* __restrict__ b3, float* __restrict__ out, int n){
  int i = blockIdx.x*256 + threadIdx.x;
  if (i >= n) return;
  float acc = y3[i];
  size_t base = (size_t)i*BK;
  int m = min(cnt[i], BK);
  for (int j = 0; j < m; ++j){
    unsigned int e = csr[base + j];
    acc = fmaf(edge_w(e), y3[e & 0x1FFFF], acc);
  }
  out[i] = fmaf(dinv[i], acc, b3[0]);
}

extern "C" void kernel_launch(void* const* d_in, const int* in_sizes, int n_in,
                              void* d_out, int out_size, void* d_ws, size_t ws_size,
                              hipStream_t stream){
  const float* x    = (const float*)d_in[0];
  const int*   ei   = (const int*)  d_in[1];
  const float* attr = (const float*)d_in[2];
  const float* W1   = (const float*)d_in[3];
  const float* b1   = (const float*)d_in[4];
  const float* g1   = (const float*)d_in[5];
  const float* be1  = (const float*)d_in[6];
  const float* W2   = (const float*)d_in[7];
  const float* b2   = (const float*)d_in[8];
  const float* g2   = (const float*)d_in[9];
  const float* be2  = (const float*)d_in[10];
  const float* W3   = (const float*)d_in[11];
  const float* b3   = (const float*)d_in[12];
  float* out = (float*)d_out;

  const int N = in_sizes[0] / HID;   // 100000
  const int E = in_sizes[2];         // 1600000
  const int nbins = (N + NPB - 1) / NPB;   // 782

  char* w = (char*)d_ws;
  auto take = [&](size_t bytes) -> char* { char* p = w; w += alignup(bytes); return p; };
  int*   binCur = (int*)  take((size_t)NBMAX*4);
  int*   cnt    = (int*)  take((size_t)N*4);
  float* dinv   = (float*)take((size_t)N*4);
  float* stats1 = (float*)take(256*4);
  float* stats2 = (float*)take(256*4);
  unsigned short* wt1 = (unsigned short*)take(128*128*2);
  unsigned short* wt2 = (unsigned short*)take(128*128*2);
  int2*  binbuf = (int2*) take((size_t)nbins*BINCAP*8);    // 15.2 MB
  unsigned int* csr = (unsigned int*)take((size_t)N*BK*4); // 19.2 MB packed
  float* y3     = (float*)take((size_t)N*4);
  unsigned int* bufA = (unsigned int*)take((size_t)N*64*4);  // bf16 pairs [N,64]
  unsigned int* bufB = (unsigned int*)take((size_t)N*64*4);  // bf16 pairs [N,64]
  (void)ws_size; (void)n_in; (void)out_size;

  int nbN = (N + 255)/256;           // 391
  int nbA = (E + CH_A - 1)/CH_A;     // 391
  int nbG = (N + 127)/128;           // 782 gemm blocks

  // preprocessing: wt transposes + zero-init; counting-sort; scaled gemm1
  k_wtprep2  <<<128,   256, 0, stream>>>(W1, W2, wt1, wt2, stats1, stats2, binCur);
  k_partA    <<<nbA,   256, 0, stream>>>(ei, attr, binCur, binbuf, E);
  k_partB    <<<nbins, 256, 0, stream>>>(binbuf, binCur, csr, cnt, dinv, N);
  k_gemm_mfma_s<<<nbG, 256, 0, stream>>>(x, wt1, dinv, bufA, N);

  // layer 1 (gather + fused BN1 stats)
  k_gatherBN <<<GB_GATHER, 256, 0, stream>>>(bufA, csr, cnt, dinv, b1, bufB, stats1, N);

  // layer 2 (BN1 finalize inlined; BN1+ReLU fused into gemm A-load)
  k_gemm_mfma_bn16_s<<<nbG, 256, 0, stream>>>(bufB, wt2, stats1, g1, be1, dinv, bufA, N);
  k_gatherBN <<<GB_GATHER, 256, 0, stream>>>(bufA, csr, cnt, dinv, b2, bufB, stats2, N);

  // layer 3 (BN2 finalize inlined into the 128->1 dot, dinv-scaled)
  k_dotW3    <<<(N+7)/8, 256, 0, stream>>>(bufB, stats2, g2, be2, W3, dinv, y3, N);
  k_gather1  <<<nbN, 256, 0, stream>>>(y3, csr, cnt, dinv, b3, out, N);
}

// Round 22
// 360.442 us; speedup vs baseline: 1.0519x; 1.0519x over previous
//
#include <hip/hip_runtime.h>
#include <hip/hip_bf16.h>

// GCN 3-layer forward, MI355X. Round 22 = r20 RESTORED (361us best).
// r21's bnstats-into-gather fusion REVERTED: 16 loop-carried stats
// accumulators serialized the grid-stride loop (occ 68->41%, VALUBusy
// 47->23%, gather 63->112us). Separate bnstats (~10us) is cheaper.
//  - Direct-scatter partA (8KB LDS, full occupancy), counting-sort partB,
//    packed 4B edges (src|bf16 attr), y=dinv*xw convention, BK=48 buckets,
//    bf16 hidden states, LDS-free MFMA GEMMs with pre-transposed bf16 W,
//    zero-init + BN-finalize fusions. 11 dispatches.

#define HID 128
#define BN_EPS 1e-5f
#define BK 48          // bucket capacity (P(Poisson(16)>48) ~ 1e-10)
#define NPB 128        // nodes per bin
#define NBMAX 1024     // max bins supported (N <= 131072)
#define CH_A 4096      // edges per partA block
#define BINCAP 2432    // bin edge capacity (mean 2048, +8.5 sigma)

typedef __attribute__((ext_vector_type(8))) short bf16x8;
typedef __attribute__((ext_vector_type(4))) float f32x4;

static inline size_t alignup(size_t x){ return (x + 255) & ~(size_t)255; }

// ---------------- helpers ----------------

static __device__ inline float2 bf16pair(unsigned int u){
  __hip_bfloat162 h = *(__hip_bfloat162*)&u;
  return __bfloat1622float2(h);
}

static __device__ inline unsigned int packpair(float x, float y){
  __hip_bfloat162 p = __float22bfloat162_rn({x, y});
  return *(unsigned int*)&p;
}

static __device__ inline uint2 pack_bf16x4(float4 a){
  uint2 r;
  r.x = packpair(a.x, a.y);
  r.y = packpair(a.z, a.w);
  return r;
}

static __device__ inline unsigned short bfbits(float v){
  __hip_bfloat16 h = __float2bfloat16(v);
  return *(unsigned short*)&h;
}

// decode packed edge: src = e & 0x1FFFF; w = float(bf16 bits = e>>17, sign 0)
static __device__ inline float edge_w(unsigned int e){
  unsigned int fb = (e >> 17) << 16;
  return __uint_as_float(fb);
}

// weight transposes + all zero-init in one launch: 128 blocks x 256 threads.
__global__ void k_wtprep2(const float* __restrict__ W1, const float* __restrict__ W2,
                          unsigned short* __restrict__ wt1, unsigned short* __restrict__ wt2,
                          float* __restrict__ stats1, float* __restrict__ stats2,
                          int* __restrict__ binCur){
  int idx = blockIdx.x*256 + threadIdx.x;   // 0..32767
  if (idx < 256) stats1[idx] = 0.f;
  else if (idx < 512) stats2[idx - 256] = 0.f;
  else if (idx < 512 + NBMAX) binCur[idx - 512] = 0;
  const float* Wg = (idx < 16384) ? W1 : W2;
  unsigned short* WTg = (idx < 16384) ? wt1 : wt2;
  int i = idx & 16383;
  int k   = i >> 7;
  int col = i & 127;
  WTg[(size_t)col*128 + k] = bfbits(Wg[(size_t)k*128 + col]);
}

// ---------------- CSR build partA: histogram + direct scatter ----------------

__global__ __launch_bounds__(256) void k_partA(const int* __restrict__ ei,
    const float* __restrict__ attr, int* __restrict__ binCur,
    int2* __restrict__ binbuf, int E){
  __shared__ int hist[NBMAX];    // pass1: histogram; pass2: local cursor
  __shared__ int gbase[NBMAX];
  int e0 = blockIdx.x * CH_A;
  for (int b = threadIdx.x; b < NBMAX; b += 256) hist[b] = 0;
  __syncthreads();
  #pragma unroll
  for (int k = 0; k < CH_A/256; ++k){
    int e = e0 + k*256 + threadIdx.x;
    if (e < E) atomicAdd(&hist[ei[E + e] >> 7], 1);
  }
  __syncthreads();
  for (int b = threadIdx.x; b < NBMAX; b += 256){
    int h = hist[b];
    gbase[b] = h ? atomicAdd(&binCur[b], h) : 0;
    hist[b] = 0;
  }
  __syncthreads();
  #pragma unroll
  for (int k = 0; k < CH_A/256; ++k){
    int e = e0 + k*256 + threadIdx.x;
    if (e < E){
      int d = ei[E + e];
      int s = ei[e];
      int bin = d >> 7;
      int p = atomicAdd(&hist[bin], 1);
      int off = gbase[bin] + p;
      if (off < BINCAP)
        binbuf[(size_t)bin*BINCAP + off] =
            make_int2(s | ((d & 127) << 17), __float_as_int(attr[e]));
    }
  }
}

// per bin: LDS node-buckets (packed 4B) + degsum -> dinv, dense writeout.
__global__ __launch_bounds__(256) void k_partB(const int2* __restrict__ binbuf,
    const int* __restrict__ binCur, unsigned int* __restrict__ csr,
    int* __restrict__ cnt, float* __restrict__ dinv, int N){
  __shared__ unsigned int lb[NPB*BK];   // 24 KB
  __shared__ int lcnt[NPB];
  int bin = blockIdx.x;
  int node0 = bin * NPB;
  for (int i = threadIdx.x; i < NPB; i += 256) lcnt[i] = 0;
  __syncthreads();
  int m = min(binCur[bin], BINCAP);
  for (int i = threadIdx.x; i < m; i += 256){
    int2 rec = binbuf[(size_t)bin*BINCAP + i];
    int dlo = (rec.x >> 17) & 127;
    int s   = rec.x & 0x1FFFF;
    unsigned int wb = bfbits(__int_as_float(rec.y)) & 0x7FFF;
    int p = atomicAdd(&lcnt[dlo], 1);
    if (p < BK) lb[dlo*BK + p] = (unsigned int)s | (wb << 17);
  }
  __syncthreads();
  if (threadIdx.x < NPB){
    int node = node0 + threadIdx.x;
    if (node < N){
      int c = min(lcnt[threadIdx.x], BK);
      float s = 0.f;
      for (int k = 0; k < c; ++k) s += edge_w(lb[threadIdx.x*BK + k]);
      cnt[node] = c;
      dinv[node] = 1.0f / sqrtf(1.0f + s);
    }
  }
  int lim = min(NPB, N - node0) * BK;
  for (int i = threadIdx.x; i < lim; i += 256)
    csr[(size_t)node0*BK + i] = lb[i];
}

// ---------------- MFMA GEMM (no LDS staging; optional inline BN coef) ------
// C[n,128](bf16 pairs, node-major) = dinv[row] * ( act(A[n,128]) @ W ).
template<bool BN, bool AB16>
__device__ inline void gemm_body(const void* __restrict__ Av,
    const unsigned short* __restrict__ WTg,
    const float* __restrict__ stats, const float* __restrict__ gamma,
    const float* __restrict__ beta, const float* __restrict__ dinv,
    unsigned int* __restrict__ C, int n, int bid){
  __shared__ float coefL[256];
  if (BN){
    if (threadIdx.x < 128){
      int c = threadIdx.x;
      float inv_n = 1.0f / (float)n;
      float mean = stats[c] * inv_n;
      float var = fmaxf(stats[128 + c] * inv_n - mean*mean, 0.f);
      float sc = gamma[c] / sqrtf(var + BN_EPS);
      coefL[c] = sc;
      coefL[128 + c] = fmaf(-mean, sc, beta[c]);
    }
    __syncthreads();
  }
  int lane = threadIdx.x & 63;
  int wv4  = threadIdx.x >> 6;      // wave 0..3
  int l16  = lane & 15;
  int kg   = lane >> 4;             // 0..3
  int row_base = bid*128 + wv4*32;
  int nm1 = n - 1;
  int a0row = min(row_base + l16,      nm1);
  int a1row = min(row_base + 16 + l16, nm1);

  f32x4 acc[2][8] = {};
  #pragma unroll
  for (int k0 = 0; k0 < 128; k0 += 32){
    int k = k0 + kg*8;
    float4 sca, scb, sha, shb;
    if (BN){
      sca = *(const float4*)(coefL + k);
      scb = *(const float4*)(coefL + k + 4);
      sha = *(const float4*)(coefL + 128 + k);
      shb = *(const float4*)(coefL + 128 + k + 4);
    }
    bf16x8 a0, a1;
    if constexpr (AB16){
      const unsigned int* A = (const unsigned int*)Av;
      uint4 u0 = *(const uint4*)(A + (size_t)a0row*64 + (k >> 1));
      uint4 u1 = *(const uint4*)(A + (size_t)a1row*64 + (k >> 1));
      #pragma unroll
      for (int half = 0; half < 2; ++half){
        uint4 u = half ? u1 : u0;
        float2 p0 = bf16pair(u.x), p1 = bf16pair(u.y);
        float2 p2 = bf16pair(u.z), p3 = bf16pair(u.w);
        if (BN){
          p0.x = fmaxf(fmaf(p0.x, sca.x, sha.x), 0.f);
          p0.y = fmaxf(fmaf(p0.y, sca.y, sha.y), 0.f);
          p1.x = fmaxf(fmaf(p1.x, sca.z, sha.z), 0.f);
          p1.y = fmaxf(fmaf(p1.y, sca.w, sha.w), 0.f);
          p2.x = fmaxf(fmaf(p2.x, scb.x, shb.x), 0.f);
          p2.y = fmaxf(fmaf(p2.y, scb.y, shb.y), 0.f);
          p3.x = fmaxf(fmaf(p3.x, scb.z, shb.z), 0.f);
          p3.y = fmaxf(fmaf(p3.y, scb.w, shb.w), 0.f);
        }
        union { bf16x8 v; unsigned int u[4]; } c;
        c.u[0] = packpair(p0.x, p0.y);
        c.u[1] = packpair(p1.x, p1.y);
        c.u[2] = packpair(p2.x, p2.y);
        c.u[3] = packpair(p3.x, p3.y);
        if (half) a1 = c.v; else a0 = c.v;
      }
    } else {
      const float* A = (const float*)Av;
      float4 lo0 = *(const float4*)(A + (size_t)a0row*HID + k);
      float4 hi0 = *(const float4*)(A + (size_t)a0row*HID + k + 4);
      float4 lo1 = *(const float4*)(A + (size_t)a1row*HID + k);
      float4 hi1 = *(const float4*)(A + (size_t)a1row*HID + k + 4);
      union { bf16x8 v; uint2 u[2]; } a0c, a1c;
      a0c.u[0] = pack_bf16x4(lo0); a0c.u[1] = pack_bf16x4(hi0);
      a1c.u[0] = pack_bf16x4(lo1); a1c.u[1] = pack_bf16x4(hi1);
      a0 = a0c.v; a1 = a1c.v;
    }
    #pragma unroll
    for (int ct = 0; ct < 8; ++ct){
      int col = ct*16 + l16;
      bf16x8 b = *(const bf16x8*)(WTg + (size_t)col*128 + k);
      acc[0][ct] = __builtin_amdgcn_mfma_f32_16x16x32_bf16(a0, b, acc[0][ct], 0,0,0);
      acc[1][ct] = __builtin_amdgcn_mfma_f32_16x16x32_bf16(a1, b, acc[1][ct], 0,0,0);
    }
  }

  #pragma unroll
  for (int rt = 0; rt < 2; ++rt){
    int growb = row_base + rt*16 + kg*4;
    #pragma unroll
    for (int r = 0; r < 4; ++r){
      int grow = growb + r;
      bool ok = (grow < n) && !(lane & 1);
      float dv = ok ? dinv[grow] : 0.f;
      #pragma unroll
      for (int ct = 0; ct < 8; ++ct){
        float v = acc[rt][ct][r];
        float o = __shfl_xor(v, 1);
        if (ok)
          C[(size_t)grow*64 + ct*8 + (l16 >> 1)] = packpair(v*dv, o*dv);
      }
    }
  }
}

__global__ __launch_bounds__(256) void k_gemm_mfma_s(const float* __restrict__ A,
    const unsigned short* __restrict__ WTg, const float* __restrict__ dinv,
    unsigned int* __restrict__ C, int n){
  gemm_body<false,false>(A, WTg, nullptr, nullptr, nullptr, dinv, C, n, blockIdx.x);
}

__global__ __launch_bounds__(256) void k_gemm_mfma_bn16_s(const unsigned int* __restrict__ A,
    const unsigned short* __restrict__ WTg, const float* __restrict__ stats,
    const float* __restrict__ gamma, const float* __restrict__ beta,
    const float* __restrict__ dinv, unsigned int* __restrict__ C, int n){
  gemm_body<true,true>(A, WTg, stats, gamma, beta, dinv, C, n, blockIdx.x);
}

// ---------------- gather / BN / final ----------------

struct Acc8 { float a0,a1,a2,a3,a4,a5,a6,a7; };

static __device__ inline void fma8(Acc8& a, uint4 v, float wt){
  float2 p0 = bf16pair(v.x), p1 = bf16pair(v.y);
  float2 p2 = bf16pair(v.z), p3 = bf16pair(v.w);
  a.a0 = fmaf(wt, p0.x, a.a0); a.a1 = fmaf(wt, p0.y, a.a1);
  a.a2 = fmaf(wt, p1.x, a.a2); a.a3 = fmaf(wt, p1.y, a.a3);
  a.a4 = fmaf(wt, p2.x, a.a4); a.a5 = fmaf(wt, p2.y, a.a5);
  a.a6 = fmaf(wt, p3.x, a.a6); a.a7 = fmaf(wt, p3.y, a.a7);
}

// out[node] = pack( b + dinv[node]*( y[node] + sum_j attr_j*y[src_j] ) )
__global__ __launch_bounds__(256) void k_gather128(const unsigned int* __restrict__ yb,
    const unsigned int* __restrict__ csr, const int* __restrict__ cnt,
    const float* __restrict__ dinv, const float* __restrict__ bias,
    unsigned int* __restrict__ out, int n){
  int node = blockIdx.x*4 + (threadIdx.x >> 6);
  int lane = threadIdx.x & 63;
  if (node >= n) return;
  int l16 = lane & 15;
  int eg  = lane >> 4;
  size_t base = (size_t)node*BK;
  int m = min(cnt[node], BK);
  Acc8 a = {0,0,0,0,0,0,0,0};
  float di = 0.f;
  float4 b0 = {0,0,0,0}, b1 = {0,0,0,0};
  if (eg == 0){
    di = dinv[node];
    uint4 sv = *(const uint4*)(yb + (size_t)node*64 + l16*4);
    b0 = *(const float4*)(bias + l16*8);
    b1 = *(const float4*)(bias + l16*8 + 4);
    float2 p0 = bf16pair(sv.x), p1 = bf16pair(sv.y);
    float2 p2 = bf16pair(sv.z), p3 = bf16pair(sv.w);
    a.a0 = p0.x; a.a1 = p0.y; a.a2 = p1.x; a.a3 = p1.y;
    a.a4 = p2.x; a.a5 = p2.y; a.a6 = p3.x; a.a7 = p3.y;
  }
  int j = eg;
  for (; j + 12 < m; j += 16){
    unsigned int e0 = csr[base + j];
    unsigned int e1 = csr[base + j + 4];
    unsigned int e2 = csr[base + j + 8];
    unsigned int e3 = csr[base + j + 12];
    uint4 v0 = *(const uint4*)(yb + (size_t)(e0 & 0x1FFFF)*64 + l16*4);
    uint4 v1 = *(const uint4*)(yb + (size_t)(e1 & 0x1FFFF)*64 + l16*4);
    uint4 v2 = *(const uint4*)(yb + (size_t)(e2 & 0x1FFFF)*64 + l16*4);
    uint4 v3 = *(const uint4*)(yb + (size_t)(e3 & 0x1FFFF)*64 + l16*4);
    fma8(a, v0, edge_w(e0));
    fma8(a, v1, edge_w(e1));
    fma8(a, v2, edge_w(e2));
    fma8(a, v3, edge_w(e3));
  }
  for (; j < m; j += 4){
    unsigned int ea = csr[base + j];
    uint4 va = *(const uint4*)(yb + (size_t)(ea & 0x1FFFF)*64 + l16*4);
    fma8(a, va, edge_w(ea));
  }
  a.a0 += __shfl_xor(a.a0, 16); a.a1 += __shfl_xor(a.a1, 16);
  a.a2 += __shfl_xor(a.a2, 16); a.a3 += __shfl_xor(a.a3, 16);
  a.a4 += __shfl_xor(a.a4, 16); a.a5 += __shfl_xor(a.a5, 16);
  a.a6 += __shfl_xor(a.a6, 16); a.a7 += __shfl_xor(a.a7, 16);
  a.a0 += __shfl_xor(a.a0, 32); a.a1 += __shfl_xor(a.a1, 32);
  a.a2 += __shfl_xor(a.a2, 32); a.a3 += __shfl_xor(a.a3, 32);
  a.a4 += __shfl_xor(a.a4, 32); a.a5 += __shfl_xor(a.a5, 32);
  a.a6 += __shfl_xor(a.a6, 32); a.a7 += __shfl_xor(a.a7, 32);
  if (eg == 0){
    uint4 r;
    r.x = packpair(fmaf(di, a.a0, b0.x), fmaf(di, a.a1, b0.y));
    r.y = packpair(fmaf(di, a.a2, b0.z), fmaf(di, a.a3, b0.w));
    r.z = packpair(fmaf(di, a.a4, b1.x), fmaf(di, a.a5, b1.y));
    r.w = packpair(fmaf(di, a.a6, b1.z), fmaf(di, a.a7, b1.w));
    *(uint4*)(out + (size_t)node*64 + l16*4) = r;
  }
}

// BN stats over bf16 h: thread handles channel pair p = tid&63.
__global__ __launch_bounds__(256) void k_bnstats(const unsigned int* __restrict__ h,
                                                 float* stats, int n){
  __shared__ float ls0[256], ls1[256], lq0[256], lq1[256];
  int p  = threadIdx.x & 63;
  int r0 = blockIdx.x*4 + (threadIdx.x >> 6);
  float s0=0.f, s1=0.f, q0=0.f, q1=0.f;
  for (int r = r0; r < n; r += gridDim.x*4){
    float2 v = bf16pair(h[(size_t)r*64 + p]);
    s0 += v.x; q0 = fmaf(v.x, v.x, q0);
    s1 += v.y; q1 = fmaf(v.y, v.y, q1);
  }
  ls0[threadIdx.x]=s0; ls1[threadIdx.x]=s1; lq0[threadIdx.x]=q0; lq1[threadIdx.x]=q1;
  __syncthreads();
  if (threadIdx.x < 64){
    int t = threadIdx.x;
    s0 = ls0[t]+ls0[t+64]+ls0[t+128]+ls0[t+192];
    s1 = ls1[t]+ls1[t+64]+ls1[t+128]+ls1[t+192];
    q0 = lq0[t]+lq0[t+64]+lq0[t+128]+lq0[t+192];
    q1 = lq1[t]+lq1[t+64]+lq1[t+128]+lq1[t+192];
    atomicAdd(&stats[2*t],       s0);
    atomicAdd(&stats[2*t+1],     s1);
    atomicAdd(&stats[128+2*t],   q0);
    atomicAdd(&stats[128+2*t+1], q1);
  }
}

// y3[row] = dinv[row] * sum_c relu(bn2(h[row][c])) * W3[c]; BN coef inline.
__global__ __launch_bounds__(256) void k_dotW3(const unsigned int* __restrict__ h,
    const float* __restrict__ stats, const float* __restrict__ gamma,
    const float* __restrict__ beta, const float* __restrict__ W3,
    const float* __restrict__ dinv, float* __restrict__ y3, int n){
  __shared__ float coefL[256];
  if (threadIdx.x < 128){
    int c = threadIdx.x;
    float inv_n = 1.0f / (float)n;
    float mean = stats[c] * inv_n;
    float var = fmaxf(stats[128 + c] * inv_n - mean*mean, 0.f);
    float sc = gamma[c] / sqrtf(var + BN_EPS);
    coefL[c] = sc;
    coefL[128 + c] = fmaf(-mean, sc, beta[c]);
  }
  __syncthreads();
  int lane = threadIdx.x & 31;
  int row = blockIdx.x*8 + (threadIdx.x >> 5);
  if (row >= n) return;
  uint2 u = *(const uint2*)(h + (size_t)row*64 + lane*2);
  float2 va = bf16pair(u.x), vb = bf16pair(u.y);
  float4 sc = *(const float4*)(coefL + lane*4);
  float4 sh = *(const float4*)(coefL + 128 + lane*4);
  float4 w  = *(const float4*)(W3 + lane*4);
  float acc = fmaxf(fmaf(va.x, sc.x, sh.x), 0.f) * w.x
            + fmaxf(fmaf(va.y, sc.y, sh.y), 0.f) * w.y
            + fmaxf(fmaf(vb.x, sc.z, sh.z), 0.f) * w.z
            + fmaxf(fmaf(vb.y, sc.w, sh.w), 0.f) * w.w;
  #pragma unroll
  for (int mm = 1; mm < 32; mm <<= 1) acc += __shfl_xor(acc, mm, 32);
  if (lane == 0) y3[row] = acc * dinv[row];
}

__global__ void k_gather1(const float* __restrict__ y3, const unsigned int* __restrict__ csr,
    const int* __restrict__ cnt, const float* __restrict__ dinv,
    const float* __restrict__ b3, float* __restrict__ out, int n){
  int i = blockIdx.x*256 + threadIdx.x;
  if (i >= n) return;
  float acc = y3[i];
  size_t base = (size_t)i*BK;
  int m = min(cnt[i], BK);
  for (int j = 0; j < m; ++j){
    unsigned int e = csr[base + j];
    acc = fmaf(edge_w(e), y3[e & 0x1FFFF], acc);
  }
  out[i] = fmaf(dinv[i], acc, b3[0]);
}

extern "C" void kernel_launch(void* const* d_in, const int* in_sizes, int n_in,
                              void* d_out, int out_size, void* d_ws, size_t ws_size,
                              hipStream_t stream){
  const float* x    = (const float*)d_in[0];
  const int*   ei   = (const int*)  d_in[1];
  const float* attr = (const float*)d_in[2];
  const float* W1   = (const float*)d_in[3];
  const float* b1   = (const float*)d_in[4];
  const float* g1   = (const float*)d_in[5];
  const float* be1  = (const float*)d_in[6];
  const float* W2   = (const float*)d_in[7];
  const float* b2   = (const float*)d_in[8];
  const float* g2   = (const float*)d_in[9];
  const float* be2  = (const float*)d_in[10];
  const float* W3   = (const float*)d_in[11];
  const float* b3   = (const float*)d_in[12];
  float* out = (float*)d_out;

  const int N = in_sizes[0] / HID;   // 100000
  const int E = in_sizes[2];         // 1600000
  const int nbins = (N + NPB - 1) / NPB;   // 782

  char* w = (char*)d_ws;
  auto take = [&](size_t bytes) -> char* { char* p = w; w += alignup(bytes); return p; };
  int*   binCur = (int*)  take((size_t)NBMAX*4);
  int*   cnt    = (int*)  take((size_t)N*4);
  float* dinv   = (float*)take((size_t)N*4);
  float* stats1 = (float*)take(256*4);
  float* stats2 = (float*)take(256*4);
  unsigned short* wt1 = (unsigned short*)take(128*128*2);
  unsigned short* wt2 = (unsigned short*)take(128*128*2);
  int2*  binbuf = (int2*) take((size_t)nbins*BINCAP*8);    // 15.2 MB
  unsigned int* csr = (unsigned int*)take((size_t)N*BK*4); // 19.2 MB packed
  float* y3     = (float*)take((size_t)N*4);
  unsigned int* bufA = (unsigned int*)take((size_t)N*64*4);  // bf16 pairs [N,64]
  unsigned int* bufB = (unsigned int*)take((size_t)N*64*4);  // bf16 pairs [N,64]
  (void)ws_size; (void)n_in; (void)out_size;

  int nbN = (N + 255)/256;           // 391
  int nbA = (E + CH_A - 1)/CH_A;     // 391
  int nbG = (N + 127)/128;           // 782 gemm blocks

  // preprocessing: wt transposes + zero-init; counting-sort; scaled gemm1
  k_wtprep2  <<<128,   256, 0, stream>>>(W1, W2, wt1, wt2, stats1, stats2, binCur);
  k_partA    <<<nbA,   256, 0, stream>>>(ei, attr, binCur, binbuf, E);
  k_partB    <<<nbins, 256, 0, stream>>>(binbuf, binCur, csr, cnt, dinv, N);
  k_gemm_mfma_s<<<nbG, 256, 0, stream>>>(x, wt1, dinv, bufA, N);

  // layer 1
  k_gather128<<<(N+3)/4, 256, 0, stream>>>(bufA, csr, cnt, dinv, b1, bufB, N);
  k_bnstats  <<<512, 256, 0, stream>>>(bufB, stats1, N);

  // layer 2 (BN1 finalize inlined; BN1+ReLU fused into gemm A-load)
  k_gemm_mfma_bn16_s<<<nbG, 256, 0, stream>>>(bufB, wt2, stats1, g1, be1, dinv, bufA, N);
  k_gather128<<<(N+3)/4, 256, 0, stream>>>(bufA, csr, cnt, dinv, b2, bufB, N);
  k_bnstats  <<<512, 256, 0, stream>>>(bufB, stats2, N);

  // layer 3 (BN2 finalize inlined into the 128->1 dot, dinv-scaled)
  k_dotW3    <<<(N+7)/8, 256, 0, stream>>>(bufB, stats2, g2, be2, W3, dinv, y3, N);
  k_gather1  <<<nbN, 256, 0, stream>>>(y3, csr, cnt, dinv, b3, out, N);
}